// Round 3
// baseline (1098.570 us; speedup 1.0000x reference)
//
#include <hip/hip_runtime.h>

#define L 1024
#define DIM 1024
#define NB 16

typedef unsigned short u16;
typedef __attribute__((ext_vector_type(4))) float f32x4;
typedef __attribute__((ext_vector_type(8))) short s16x8;

__device__ __forceinline__ float bf2f(u16 x){
  union { unsigned u; float f; } c; c.u = ((unsigned)x) << 16; return c.f;
}
__device__ __forceinline__ u16 f2bf(float f){
  union { float f; unsigned u; } c; c.f = f;
  unsigned r = c.u + 0x7fffu + ((c.u >> 16) & 1u);
  return (u16)(r >> 16);
}
__device__ __forceinline__ void gload_lds16(const void* g, void* l){
  __builtin_amdgcn_global_load_lds(
      (const __attribute__((address_space(1))) void*)g,
      (__attribute__((address_space(3))) void*)l, 16, 0, 0);
}

// ---------------- weights fp32 -> bf16 (once) ----------------
struct WPtrs { const float* p[6]; };

__global__ __launch_bounds__(256) void k_wconv(WPtrs wp, u16* out){
  long idx = (long)blockIdx.x * blockDim.x + threadIdx.x;
  long base = idx * 4;
  int w = (int)(base >> 20);
  long off = base & ((1 << 20) - 1);
  float4 v = *(const float4*)(wp.p[w] + off);
  ushort4 o;
  o.x = f2bf(v.x); o.y = f2bf(v.y); o.z = f2bf(v.z); o.w = f2bf(v.w);
  *(ushort4*)(out + base) = o;
}

// ---------------- V [D,L] f32 -> Vt [L,D] bf16 (group-local) ----------------
__global__ __launch_bounds__(256) void k_transpose(const float* X, u16* Xt, int bo){
  __shared__ u16 tile[64][65];
  int b = blockIdx.y;
  int d0 = (blockIdx.x >> 4) * 64;
  int l0 = (blockIdx.x & 15) * 64;
  const float* Xb = X + (long)(bo + b) * DIM * L;
  u16* Xtb = Xt + (long)b * L * DIM;
  int c = threadIdx.x & 63, g = threadIdx.x >> 6;
  for (int r = g; r < 64; r += 4)
    tile[r][c] = f2bf(Xb[(long)(d0 + r) * L + l0 + c]);
  __syncthreads();
  for (int r = g; r < 64; r += 4)
    Xtb[(long)(l0 + r) * DIM + d0 + c] = tile[c][r];
}

// ---------------- T: column inv-norm rT + normalized transpose Tnt ----------------
__global__ __launch_bounds__(256) void k_tnorm(const float* T_, u16* Tnt, float* rT, int bo){
  __shared__ float red[4][64];
  __shared__ float rn[64];
  __shared__ u16 tile[64][65];
  int b = blockIdx.y; int l0 = blockIdx.x * 64;
  const float* Tb = T_ + (long)(bo + b) * DIM * L;
  int c = threadIdx.x & 63, g = threadIdx.x >> 6;
  float ss = 0.f;
  for (int d = g; d < DIM; d += 4){
    float v = Tb[(long)d * L + l0 + c];
    ss += v * v;
  }
  red[g][c] = ss; __syncthreads();
  if (g == 0){
    float n = sqrtf(red[0][c] + red[1][c] + red[2][c] + red[3][c]);
    float r = 1.0f / fmaxf(n, 1e-12f);
    rn[c] = r;
    rT[(long)b * L + l0 + c] = r;
  }
  __syncthreads();
  u16* Tntb = Tnt + (long)b * L * DIM;
  for (int ch = 0; ch < DIM / 64; ch++){
    int dbase = ch * 64;
    for (int r = g; r < 64; r += 4)
      tile[r][c] = f2bf(Tb[(long)(dbase + r) * L + l0 + c] * rn[c]);
    __syncthreads();
    for (int r = g; r < 64; r += 4)
      Tntb[(long)(l0 + r) * DIM + dbase + c] = tile[c][r];
    __syncthreads();
  }
}

// ---------------- bt-GEMM: C[m,n] = epi( sum_k A[m,k]*B[n,k] ) -> bf16 ----------------
// EPI: 0 relu | 1 exp(acc*scale) | 2 relu * Zinv[n] | 3 plain
template<int EPI>
__global__ __launch_bounds__(256) void k_gemm(const u16* A, const u16* B, u16* C,
                                              long sA_, long sB_, long sC_,
                                              const float* Zp, float scale){
  constexpr int K = 1024, NN = 1024;
  __shared__ u16 sA[128 * 32];
  __shared__ u16 sB[128 * 32];
  int tid = threadIdx.x;
  int w = tid >> 6, l = tid & 63;
  int bm = (blockIdx.x >> 3) * 128, bn = (blockIdx.x & 7) * 128;
  const u16* Ab = A + (long)blockIdx.y * sA_ + (long)bm * K;
  const u16* Bb = B + (long)blockIdx.y * sB_ + (long)bn * K;
  f32x4 acc[4][4] = {};
  int wm = (w >> 1) * 64, wn = (w & 1) * 64;
  int lr = l & 15, kb = (l >> 4) * 8;
  int srow = w * 16 + (l >> 2), scol = (l & 3) * 8;

  for (int k0 = 0; k0 < K; k0 += 32){
    __syncthreads();
    #pragma unroll
    for (int i = 0; i < 2; i++){
      gload_lds16(Ab + (long)(i * 64 + srow) * K + k0 + scol, &sA[i * 2048 + w * 512]);
      gload_lds16(Bb + (long)(i * 64 + srow) * K + k0 + scol, &sB[i * 2048 + w * 512]);
    }
    __syncthreads();
    s16x8 af[4], bfr[4];
    #pragma unroll
    for (int i = 0; i < 4; i++) af[i] = *(const s16x8*)&sA[(wm + i * 16 + lr) * 32 + kb];
    #pragma unroll
    for (int j = 0; j < 4; j++) bfr[j] = *(const s16x8*)&sB[(wn + j * 16 + lr) * 32 + kb];
    #pragma unroll
    for (int i = 0; i < 4; i++)
      #pragma unroll
      for (int j = 0; j < 4; j++)
        acc[i][j] = __builtin_amdgcn_mfma_f32_16x16x32_bf16(af[i], bfr[j], acc[i][j], 0, 0, 0);
  }

  int orow0 = bm + wm + (l >> 4) * 4;
  int ocol = bn + wn + (l & 15);
  float iz[4];
  if (EPI == 2){
    #pragma unroll
    for (int j = 0; j < 4; j++) iz[j] = Zp[(long)blockIdx.y * NN + ocol + j * 16];
  }
  u16* Cb = C + (long)blockIdx.y * sC_;
  #pragma unroll
  for (int i = 0; i < 4; i++)
    #pragma unroll
    for (int j = 0; j < 4; j++)
      #pragma unroll
      for (int r = 0; r < 4; r++){
        float v = acc[i][j][r];
        if (EPI == 0) v = fmaxf(v, 0.f);
        else if (EPI == 1) v = __expf(v * scale);
        else if (EPI == 2) v = fmaxf(v, 0.f) * iz[j];
        Cb[(long)(orow0 + i * 16 + r) * NN + ocol + j * 16] = f2bf(v);
      }
}

// ---------------- column sums of E[q,k] over q -> invZ[k] ----------------
__global__ __launch_bounds__(256) void k_colsum(const u16* E, float* invZ){
  __shared__ float red[4][64];
  int b = blockIdx.y; int k0 = blockIdx.x * 64;
  const u16* Eb = E + (long)b * L * L + k0;
  int c = threadIdx.x & 63, g = threadIdx.x >> 6;
  float z = 0.f;
  for (int q = g; q < L; q += 4) z += bf2f(Eb[(long)q * L + c]);
  red[g][c] = z; __syncthreads();
  if (g == 0)
    invZ[(long)b * L + k0 + c] = 1.0f / (red[0][c] + red[1][c] + red[2][c] + red[3][c]);
}

// ---------------- final: out = l2n(l2n(V+w1t) + l2n(T*rT+w2t)) per column ----------------
__global__ __launch_bounds__(256) void k_final(const float* V, const float* T_,
                                               const float* rT, const u16* w1t,
                                               const u16* w2t, float* out, int bo){
  __shared__ float red[3][4][64];
  __shared__ float fac[3][64];
  int b = blockIdx.y;
  long gbase = (long)(bo + b) * DIM * L + blockIdx.x * 64;
  long lbase = (long)b * DIM * L + blockIdx.x * 64;
  int c = threadIdx.x & 63, g = threadIdx.x >> 6;
  float rt = rT[(long)b * L + blockIdx.x * 64 + c];
  float s1 = 0.f, s2 = 0.f, s12 = 0.f;
  for (int d = g; d < DIM; d += 4){
    long o = (long)d * L + c;
    float a = V[gbase + o] + bf2f(w1t[lbase + o]);
    float bb = T_[gbase + o] * rt + bf2f(w2t[lbase + o]);
    s1 += a * a; s2 += bb * bb; s12 += a * bb;
  }
  red[0][g][c] = s1; red[1][g][c] = s2; red[2][g][c] = s12;
  __syncthreads();
  if (g == 0){
    float n1 = red[0][0][c] + red[0][1][c] + red[0][2][c] + red[0][3][c];
    float n2 = red[1][0][c] + red[1][1][c] + red[1][2][c] + red[1][3][c];
    float cc = red[2][0][c] + red[2][1][c] + red[2][2][c] + red[2][3][c];
    float rn1 = 1.f / fmaxf(sqrtf(n1), 1e-12f);
    float rn2 = 1.f / fmaxf(sqrtf(n2), 1e-12f);
    float n3 = n1 * rn1 * rn1 + 2.f * cc * rn1 * rn2 + n2 * rn2 * rn2;
    float rn3 = 1.f / fmaxf(sqrtf(n3), 1e-12f);
    fac[0][c] = rn1; fac[1][c] = rn2; fac[2][c] = rn3;
  }
  __syncthreads();
  float rn1 = fac[0][c], rn2 = fac[1][c], rn3 = fac[2][c];
  for (int d = g; d < DIM; d += 4){
    long o = (long)d * L + c;
    float a = V[gbase + o] + bf2f(w1t[lbase + o]);
    float bb = T_[gbase + o] * rt + bf2f(w2t[lbase + o]);
    out[gbase + o] = (a * rn1 + bb * rn2) * rn3;
  }
}

extern "C" void kernel_launch(void* const* d_in, const int* in_sizes, int n_in,
                              void* d_out, int out_size, void* d_ws, size_t ws_size,
                              hipStream_t stream) {
  const float* V = (const float*)d_in[0];
  const float* T = (const float*)d_in[1];
  char* ws = (char*)d_ws;
  const long MB = 1 << 20;
  float* out = (float*)d_out;

  // pick batch-group size so workspace fits: fixed 13MB + 14MB per batch
  int G = NB;
  while (G > 1 && (size_t)((13 + 14 * (long)G) * MB) > ws_size) G >>= 1;

  u16*   Wb   = (u16*)(ws);                         // 12MB (6 x 1M bf16)
  float* rT   = (float*)(ws + 12 * MB);             // G*L f32 (<=64KB)
  float* invZ = (float*)(ws + 12 * MB + 512 * 1024);// G*L f32 (<=64KB)
  char*  bufs = ws + 13 * MB;
  long   BUF  = (long)G * 2 * MB;                   // per-buffer bytes
  u16* Vt  = (u16*)(bufs);
  u16* Tnt = (u16*)(bufs + 1 * BUF);
  u16* qb  = (u16*)(bufs + 2 * BUF);   // also holds v1t'/v2t' (overlay)
  u16* kb  = (u16*)(bufs + 3 * BUF);
  u16* Eb  = (u16*)(bufs + 4 * BUF);
  u16* w1b = (u16*)(bufs + 5 * BUF);
  u16* w2b = (u16*)(bufs + 6 * BUF);

  WPtrs wp;
  for (int i = 0; i < 6; i++) wp.p[i] = (const float*)d_in[2 + i];
  const u16* WQ1 = Wb + 0L * MB; const u16* WK1 = Wb + 1L * MB;
  const u16* WV1 = Wb + 2L * MB; const u16* Wq2 = Wb + 3L * MB;
  const u16* Wk2 = Wb + 4L * MB; const u16* Wv2 = Wb + 5L * MB;

  long LD = (long)L * DIM, LL = (long)L * L;
  const float invsq = 0.03125f;  // 1/sqrt(1024)

  k_wconv<<<6144, 256, 0, stream>>>(wp, Wb);

  for (int bo = 0; bo < NB; bo += G){
    dim3 gg(64, G);
    k_transpose<<<dim3(256, G), 256, 0, stream>>>(V, Vt, bo);
    k_tnorm<<<dim3(16, G), 256, 0, stream>>>(T, Tnt, rT, bo);

    // side 1
    k_gemm<0><<<gg, 256, 0, stream>>>(Vt,  WQ1, qb, LD, 0, LD, nullptr, 0.f);   // q1[l,e]
    k_gemm<0><<<gg, 256, 0, stream>>>(Tnt, WK1, kb, LD, 0, LD, nullptr, 0.f);   // k1[l,e]
    k_gemm<1><<<gg, 256, 0, stream>>>(qb, kb, Eb, LD, LD, LL, nullptr, invsq);  // E=exp(S)
    k_colsum<<<dim3(16, G), 256, 0, stream>>>(Eb, invZ);
    k_gemm<2><<<gg, 256, 0, stream>>>(WV1, Tnt, qb, 0, LD, LD, invZ, 0.f);      // v1t'[e,k]
    k_gemm<3><<<gg, 256, 0, stream>>>(qb, Eb, w1b, LD, LL, LD, nullptr, 0.f);   // w1t[e,q]

    // side 2
    k_gemm<0><<<gg, 256, 0, stream>>>(Tnt, Wq2, qb, LD, 0, LD, nullptr, 0.f);   // q2[l,e]
    k_gemm<0><<<gg, 256, 0, stream>>>(Vt,  Wk2, kb, LD, 0, LD, nullptr, 0.f);   // k2[l,e]
    k_gemm<1><<<gg, 256, 0, stream>>>(qb, kb, Eb, LD, LD, LL, nullptr, invsq);
    k_colsum<<<dim3(16, G), 256, 0, stream>>>(Eb, invZ);
    k_gemm<2><<<gg, 256, 0, stream>>>(Wv2, Vt, qb, 0, LD, LD, invZ, 0.f);       // v2t'[e,k]
    k_gemm<3><<<gg, 256, 0, stream>>>(qb, Eb, w2b, LD, LL, LD, nullptr, 0.f);   // w2t[e,q]

    k_final<<<dim3(16, G), 256, 0, stream>>>(V, T, rT, w1b, w2b, out, bo);
  }
}

// Round 4
// 758.887 us; speedup vs baseline: 1.4476x; 1.4476x over previous
//
#include <hip/hip_runtime.h>

#define L 1024
#define DIM 1024
#define NB 16

typedef unsigned short u16;
typedef __attribute__((ext_vector_type(4))) float f32x4;
typedef __attribute__((ext_vector_type(8))) short s16x8;

__device__ __forceinline__ float bf2f(u16 x){
  union { unsigned u; float f; } c; c.u = ((unsigned)x) << 16; return c.f;
}
__device__ __forceinline__ u16 f2bf(float f){
  union { float f; unsigned u; } c; c.f = f;
  unsigned r = c.u + 0x7fffu + ((c.u >> 16) & 1u);
  return (u16)(r >> 16);
}
__device__ __forceinline__ void gload_lds16(const void* g, void* l){
  __builtin_amdgcn_global_load_lds(
      (const __attribute__((address_space(1))) void*)g,
      (__attribute__((address_space(3))) void*)l, 16, 0, 0);
}

// ---------------- weights fp32 -> bf16 (once) ----------------
struct WPtrs { const float* p[6]; };

__global__ __launch_bounds__(256) void k_wconv(WPtrs wp, u16* out){
  long idx = (long)blockIdx.x * blockDim.x + threadIdx.x;
  long base = idx * 4;
  int w = (int)(base >> 20);
  long off = base & ((1 << 20) - 1);
  float4 v = *(const float4*)(wp.p[w] + off);
  ushort4 o;
  o.x = f2bf(v.x); o.y = f2bf(v.y); o.z = f2bf(v.z); o.w = f2bf(v.w);
  *(ushort4*)(out + base) = o;
}

// ---------------- V [D,L] f32 -> Vt [L,D] bf16 (vectorized) ----------------
__global__ __launch_bounds__(256) void k_transpose(const float* X, u16* Xt, int bo){
  __shared__ u16 tile[64][68];
  int b = blockIdx.y;
  int d0 = (blockIdx.x >> 4) * 64;
  int l0 = (blockIdx.x & 15) * 64;
  const float* Xb = X + (long)(bo + b) * DIM * L;
  u16* Xtb = Xt + (long)b * L * DIM;
  int q = threadIdx.x & 15, g = threadIdx.x >> 4;
  for (int r = g; r < 64; r += 16){
    float4 v = *(const float4*)(Xb + (long)(d0 + r) * L + l0 + q * 4);
    ushort4 h; h.x = f2bf(v.x); h.y = f2bf(v.y); h.z = f2bf(v.z); h.w = f2bf(v.w);
    *(ushort4*)&tile[r][q * 4] = h;
  }
  __syncthreads();
  for (int r = g; r < 64; r += 16){
    ushort4 h;
    h.x = tile[q * 4 + 0][r]; h.y = tile[q * 4 + 1][r];
    h.z = tile[q * 4 + 2][r]; h.w = tile[q * 4 + 3][r];
    *(ushort4*)&Xtb[(long)(l0 + r) * DIM + d0 + q * 4] = h;
  }
}

// ---------------- T: column inv-norm rT + normalized transpose Tnt ----------------
__global__ __launch_bounds__(256) void k_tnorm(const float* T_, u16* Tnt, float* rT, int bo){
  __shared__ float red[16][16][5];
  __shared__ float rn[64];
  __shared__ u16 tile[64][68];
  int b = blockIdx.y; int l0 = blockIdx.x * 64;
  const float* Tb = T_ + (long)(bo + b) * DIM * L;
  int q = threadIdx.x & 15, g = threadIdx.x >> 4;
  f32x4 ss = {0.f, 0.f, 0.f, 0.f};
  for (int d = g; d < DIM; d += 16){
    float4 v = *(const float4*)(Tb + (long)d * L + l0 + q * 4);
    f32x4 vv = {v.x, v.y, v.z, v.w};
    ss += vv * vv;
  }
  #pragma unroll
  for (int e = 0; e < 4; e++) red[g][q][e] = ss[e];
  __syncthreads();
  if (threadIdx.x < 64){
    int c = threadIdx.x;
    float n = 0.f;
    #pragma unroll
    for (int gg = 0; gg < 16; gg++) n += red[gg][c >> 2][c & 3];
    float r = 1.0f / fmaxf(sqrtf(n), 1e-12f);
    rn[c] = r;
    rT[(long)b * L + l0 + c] = r;
  }
  __syncthreads();
  float r0 = rn[q * 4], r1 = rn[q * 4 + 1], r2 = rn[q * 4 + 2], r3 = rn[q * 4 + 3];
  u16* Tntb = Tnt + (long)b * L * DIM;
  for (int ch = 0; ch < 16; ch++){
    int dbase = ch * 64;
    for (int r = g; r < 64; r += 16){
      float4 v = *(const float4*)(Tb + (long)(dbase + r) * L + l0 + q * 4);
      ushort4 h;
      h.x = f2bf(v.x * r0); h.y = f2bf(v.y * r1);
      h.z = f2bf(v.z * r2); h.w = f2bf(v.w * r3);
      *(ushort4*)&tile[r][q * 4] = h;
    }
    __syncthreads();
    for (int r = g; r < 64; r += 16){
      ushort4 h;
      h.x = tile[q * 4 + 0][r]; h.y = tile[q * 4 + 1][r];
      h.z = tile[q * 4 + 2][r]; h.w = tile[q * 4 + 3][r];
      *(ushort4*)&Tntb[(long)(l0 + r) * DIM + dbase + q * 4] = h;
    }
    __syncthreads();
  }
}

// ---------------- bt-GEMM: C[m,n] = epi( sum_k A[m,k]*B[n,k] ) -> bf16 ----------------
// EPI: 0 relu | 1 exp(acc*scale) | 2 relu * Zinv[n] | 3 plain
template<int EPI>
__global__ __launch_bounds__(256) void k_gemm(const u16* A, const u16* B, u16* C,
                                              long sA_, long sB_, long sC_,
                                              const float* Zp, float scale){
  constexpr int K = 1024, NN = 1024;
  __shared__ u16 sA[128 * 32];
  __shared__ u16 sB[128 * 32];
  int tid = threadIdx.x;
  int w = tid >> 6, l = tid & 63;
  int bm = (blockIdx.x >> 3) * 128, bn = (blockIdx.x & 7) * 128;
  const u16* Ab = A + (long)blockIdx.y * sA_ + (long)bm * K;
  const u16* Bb = B + (long)blockIdx.y * sB_ + (long)bn * K;
  f32x4 acc[4][4] = {};
  int wm = (w >> 1) * 64, wn = (w & 1) * 64;
  int lr = l & 15, kb = (l >> 4) * 8;
  int srow = w * 16 + (l >> 2), scol = (l & 3) * 8;

  for (int k0 = 0; k0 < K; k0 += 32){
    __syncthreads();
    #pragma unroll
    for (int i = 0; i < 2; i++){
      gload_lds16(Ab + (long)(i * 64 + srow) * K + k0 + scol, &sA[i * 2048 + w * 512]);
      gload_lds16(Bb + (long)(i * 64 + srow) * K + k0 + scol, &sB[i * 2048 + w * 512]);
    }
    __syncthreads();
    s16x8 af[4], bfr[4];
    #pragma unroll
    for (int i = 0; i < 4; i++) af[i] = *(const s16x8*)&sA[(wm + i * 16 + lr) * 32 + kb];
    #pragma unroll
    for (int j = 0; j < 4; j++) bfr[j] = *(const s16x8*)&sB[(wn + j * 16 + lr) * 32 + kb];
    #pragma unroll
    for (int i = 0; i < 4; i++)
      #pragma unroll
      for (int j = 0; j < 4; j++)
        acc[i][j] = __builtin_amdgcn_mfma_f32_16x16x32_bf16(af[i], bfr[j], acc[i][j], 0, 0, 0);
  }

  int orow0 = bm + wm + (l >> 4) * 4;
  int ocol = bn + wn + (l & 15);
  float iz[4];
  if (EPI == 2){
    #pragma unroll
    for (int j = 0; j < 4; j++) iz[j] = Zp[(long)blockIdx.y * NN + ocol + j * 16];
  }
  u16* Cb = C + (long)blockIdx.y * sC_;
  #pragma unroll
  for (int i = 0; i < 4; i++)
    #pragma unroll
    for (int j = 0; j < 4; j++)
      #pragma unroll
      for (int r = 0; r < 4; r++){
        float v = acc[i][j][r];
        if (EPI == 0) v = fmaxf(v, 0.f);
        else if (EPI == 1) v = __expf(v * scale);
        else if (EPI == 2) v = fmaxf(v, 0.f) * iz[j];
        Cb[(long)(orow0 + i * 16 + r) * NN + ocol + j * 16] = f2bf(v);
      }
}

// ---------------- column sums of E[q,k] over q -> invZ[k] (vectorized) ----------------
__global__ __launch_bounds__(256) void k_colsum(const u16* E, float* invZ){
  __shared__ float red[32][8][9];
  int b = blockIdx.y; int k0 = blockIdx.x * 64;
  const u16* Eb = E + (long)b * L * L + k0;
  int co = threadIdx.x & 7, g = threadIdx.x >> 3;
  float z[8] = {0.f, 0.f, 0.f, 0.f, 0.f, 0.f, 0.f, 0.f};
  for (int qq = g; qq < L; qq += 32){
    s16x8 h = *(const s16x8*)(Eb + (long)qq * L + co * 8);
    #pragma unroll
    for (int e = 0; e < 8; e++) z[e] += bf2f((u16)h[e]);
  }
  #pragma unroll
  for (int e = 0; e < 8; e++) red[g][co][e] = z[e];
  __syncthreads();
  if (threadIdx.x < 64){
    int c = threadIdx.x;
    float s = 0.f;
    #pragma unroll
    for (int gg = 0; gg < 32; gg++) s += red[gg][c >> 3][c & 7];
    invZ[(long)b * L + k0 + c] = 1.0f / s;
  }
}

// ---------------- final: out = l2n(l2n(V+w1t) + l2n(T*rT+w2t)) per column ----------------
__global__ __launch_bounds__(1024) void k_final(const float* V, const float* T_,
                                                const float* rT, const u16* w1t,
                                                const u16* w2t, float* out, int bo){
  __shared__ float red[64][16][13];
  __shared__ float fac[3][64];
  int b = blockIdx.y;
  int c0 = blockIdx.x * 64;
  long gbase = (long)(bo + b) * DIM * L + c0;
  long lbase = (long)b * DIM * L + c0;
  int cq = threadIdx.x & 15, g = threadIdx.x >> 4;
  int coff = cq * 4;
  float4 rt4 = *(const float4*)(rT + (long)b * L + c0 + coff);
  f32x4 rtv = {rt4.x, rt4.y, rt4.z, rt4.w};
  f32x4 s1 = {0.f,0.f,0.f,0.f}, s2 = {0.f,0.f,0.f,0.f}, s12 = {0.f,0.f,0.f,0.f};
  for (int d = g; d < DIM; d += 64){
    long o = (long)d * L + coff;
    float4 v = *(const float4*)(V + gbase + o);
    float4 t = *(const float4*)(T_ + gbase + o);
    ushort4 w1 = *(const ushort4*)(w1t + lbase + o);
    ushort4 w2 = *(const ushort4*)(w2t + lbase + o);
    f32x4 a = {v.x + bf2f(w1.x), v.y + bf2f(w1.y), v.z + bf2f(w1.z), v.w + bf2f(w1.w)};
    f32x4 tt = {t.x, t.y, t.z, t.w};
    f32x4 bb = tt * rtv;
    bb[0] += bf2f(w2.x); bb[1] += bf2f(w2.y); bb[2] += bf2f(w2.z); bb[3] += bf2f(w2.w);
    s1 += a * a; s2 += bb * bb; s12 += a * bb;
  }
  #pragma unroll
  for (int e = 0; e < 4; e++){
    red[g][cq][e] = s1[e];
    red[g][cq][4 + e] = s2[e];
    red[g][cq][8 + e] = s12[e];
  }
  __syncthreads();
  if (threadIdx.x < 192){
    int q = threadIdx.x / 12, s = threadIdx.x % 12;
    float acc = 0.f;
    #pragma unroll 8
    for (int gg = 0; gg < 64; gg++) acc += red[gg][q][s];
    red[0][q][s] = acc;
  }
  __syncthreads();
  if (threadIdx.x < 64){
    int c = threadIdx.x;
    float n1 = red[0][c >> 2][c & 3];
    float n2 = red[0][c >> 2][4 + (c & 3)];
    float cc = red[0][c >> 2][8 + (c & 3)];
    float rn1 = 1.f / fmaxf(sqrtf(n1), 1e-12f);
    float rn2 = 1.f / fmaxf(sqrtf(n2), 1e-12f);
    float n3 = n1 * rn1 * rn1 + 2.f * cc * rn1 * rn2 + n2 * rn2 * rn2;
    float rn3 = 1.f / fmaxf(sqrtf(n3), 1e-12f);
    fac[0][c] = rn1; fac[1][c] = rn2; fac[2][c] = rn3;
  }
  __syncthreads();
  f32x4 f1, f2, f3;
  #pragma unroll
  for (int e = 0; e < 4; e++){
    f1[e] = fac[0][coff + e]; f2[e] = fac[1][coff + e]; f3[e] = fac[2][coff + e];
  }
  for (int d = g; d < DIM; d += 64){
    long o = (long)d * L + coff;
    float4 v = *(const float4*)(V + gbase + o);
    float4 t = *(const float4*)(T_ + gbase + o);
    ushort4 w1 = *(const ushort4*)(w1t + lbase + o);
    ushort4 w2 = *(const ushort4*)(w2t + lbase + o);
    f32x4 a = {v.x + bf2f(w1.x), v.y + bf2f(w1.y), v.z + bf2f(w1.z), v.w + bf2f(w1.w)};
    f32x4 tt = {t.x, t.y, t.z, t.w};
    f32x4 bb = tt * rtv;
    bb[0] += bf2f(w2.x); bb[1] += bf2f(w2.y); bb[2] += bf2f(w2.z); bb[3] += bf2f(w2.w);
    f32x4 r = (a * f1 + bb * f2) * f3;
    float4 st = {r[0], r[1], r[2], r[3]};
    *(float4*)(out + gbase + o) = st;
  }
}

extern "C" void kernel_launch(void* const* d_in, const int* in_sizes, int n_in,
                              void* d_out, int out_size, void* d_ws, size_t ws_size,
                              hipStream_t stream) {
  const float* V = (const float*)d_in[0];
  const float* T = (const float*)d_in[1];
  char* ws = (char*)d_ws;
  const long MB = 1 << 20;
  float* out = (float*)d_out;

  // pick batch-group size so workspace fits: fixed 13MB + 14MB per batch
  int G = NB;
  while (G > 1 && (size_t)((13 + 14 * (long)G) * MB) > ws_size) G >>= 1;

  u16*   Wb   = (u16*)(ws);                          // 12MB (6 x 1M bf16)
  float* rT   = (float*)(ws + 12 * MB);              // G*L f32 (<=64KB)
  float* invZ = (float*)(ws + 12 * MB + 512 * 1024); // G*L f32 (<=64KB)
  char*  bufs = ws + 13 * MB;
  long   BUF  = (long)G * 2 * MB;                    // per-buffer bytes
  u16* Vt  = (u16*)(bufs);
  u16* Tnt = (u16*)(bufs + 1 * BUF);
  u16* qb  = (u16*)(bufs + 2 * BUF);   // also holds v1t'/v2t' (overlay)
  u16* kb  = (u16*)(bufs + 3 * BUF);
  u16* Eb  = (u16*)(bufs + 4 * BUF);
  u16* w1b = (u16*)(bufs + 5 * BUF);
  u16* w2b = (u16*)(bufs + 6 * BUF);

  WPtrs wp;
  for (int i = 0; i < 6; i++) wp.p[i] = (const float*)d_in[2 + i];
  const u16* WQ1 = Wb + 0L * MB; const u16* WK1 = Wb + 1L * MB;
  const u16* WV1 = Wb + 2L * MB; const u16* Wq2 = Wb + 3L * MB;
  const u16* Wk2 = Wb + 4L * MB; const u16* Wv2 = Wb + 5L * MB;

  long LD = (long)L * DIM, LL = (long)L * L;
  const float invsq = 0.03125f;  // 1/sqrt(1024)

  k_wconv<<<6144, 256, 0, stream>>>(wp, Wb);

  for (int bo = 0; bo < NB; bo += G){
    dim3 gg(64, G);
    k_transpose<<<dim3(256, G), 256, 0, stream>>>(V, Vt, bo);
    k_tnorm<<<dim3(16, G), 256, 0, stream>>>(T, Tnt, rT, bo);

    // side 1
    k_gemm<0><<<gg, 256, 0, stream>>>(Vt,  WQ1, qb, LD, 0, LD, nullptr, 0.f);   // q1[l,e]
    k_gemm<0><<<gg, 256, 0, stream>>>(Tnt, WK1, kb, LD, 0, LD, nullptr, 0.f);   // k1[l,e]
    k_gemm<1><<<gg, 256, 0, stream>>>(qb, kb, Eb, LD, LD, LL, nullptr, invsq);  // E=exp(S)
    k_colsum<<<dim3(16, G), 256, 0, stream>>>(Eb, invZ);
    k_gemm<2><<<gg, 256, 0, stream>>>(WV1, Tnt, qb, 0, LD, LD, invZ, 0.f);      // v1t'[e,k]
    k_gemm<3><<<gg, 256, 0, stream>>>(qb, Eb, w1b, LD, LL, LD, nullptr, 0.f);   // w1t[e,q]

    // side 2
    k_gemm<0><<<gg, 256, 0, stream>>>(Tnt, Wq2, qb, LD, 0, LD, nullptr, 0.f);   // q2[l,e]
    k_gemm<0><<<gg, 256, 0, stream>>>(Vt,  Wk2, kb, LD, 0, LD, nullptr, 0.f);   // k2[l,e]
    k_gemm<1><<<gg, 256, 0, stream>>>(qb, kb, Eb, LD, LD, LL, nullptr, invsq);
    k_colsum<<<dim3(16, G), 256, 0, stream>>>(Eb, invZ);
    k_gemm<2><<<gg, 256, 0, stream>>>(Wv2, Vt, qb, 0, LD, LD, invZ, 0.f);       // v2t'[e,k]
    k_gemm<3><<<gg, 256, 0, stream>>>(qb, Eb, w2b, LD, LL, LD, nullptr, 0.f);   // w2t[e,q]

    k_final<<<dim3(16, G), 1024, 0, stream>>>(V, T, rT, w1b, w2b, out, bo);
  }
}

// Round 5
// 567.360 us; speedup vs baseline: 1.9363x; 1.3376x over previous
//
#include <hip/hip_runtime.h>

#define L 1024
#define DIM 1024
#define NB 16

typedef unsigned short u16;
typedef __attribute__((ext_vector_type(4))) float f32x4;
typedef __attribute__((ext_vector_type(8))) short s16x8;

__device__ __forceinline__ float bf2f(u16 x){
  union { unsigned u; float f; } c; c.u = ((unsigned)x) << 16; return c.f;
}
__device__ __forceinline__ u16 f2bf(float f){
  union { float f; unsigned u; } c; c.f = f;
  unsigned r = c.u + 0x7fffu + ((c.u >> 16) & 1u);
  return (u16)(r >> 16);
}
__device__ __forceinline__ void gload_lds16(const void* g, void* l){
  __builtin_amdgcn_global_load_lds(
      (const __attribute__((address_space(1))) void*)g,
      (__attribute__((address_space(3))) void*)l, 16, 0, 0);
}

// ---------------- weights fp32 -> bf16 (once) ----------------
struct WPtrs { const float* p[6]; };

__global__ __launch_bounds__(256) void k_wconv(WPtrs wp, u16* out){
  long idx = (long)blockIdx.x * blockDim.x + threadIdx.x;
  long base = idx * 4;
  int w = (int)(base >> 20);
  long off = base & ((1 << 20) - 1);
  float4 v = *(const float4*)(wp.p[w] + off);
  ushort4 o;
  o.x = f2bf(v.x); o.y = f2bf(v.y); o.z = f2bf(v.z); o.w = f2bf(v.w);
  *(ushort4*)(out + base) = o;
}

// ---------------- V [D,L] f32 -> Vt [L,D] bf16 (vectorized) ----------------
__global__ __launch_bounds__(256) void k_transpose(const float* X, u16* Xt, int bo){
  __shared__ u16 tile[64][68];
  int b = blockIdx.y;
  int d0 = (blockIdx.x >> 4) * 64;
  int l0 = (blockIdx.x & 15) * 64;
  const float* Xb = X + (long)(bo + b) * DIM * L;
  u16* Xtb = Xt + (long)b * L * DIM;
  int q = threadIdx.x & 15, g = threadIdx.x >> 4;
  for (int r = g; r < 64; r += 16){
    float4 v = *(const float4*)(Xb + (long)(d0 + r) * L + l0 + q * 4);
    ushort4 h; h.x = f2bf(v.x); h.y = f2bf(v.y); h.z = f2bf(v.z); h.w = f2bf(v.w);
    *(ushort4*)&tile[r][q * 4] = h;
  }
  __syncthreads();
  for (int r = g; r < 64; r += 16){
    ushort4 h;
    h.x = tile[q * 4 + 0][r]; h.y = tile[q * 4 + 1][r];
    h.z = tile[q * 4 + 2][r]; h.w = tile[q * 4 + 3][r];
    *(ushort4*)&Xtb[(long)(l0 + r) * DIM + d0 + q * 4] = h;
  }
}

// ---------------- T: column inv-norm rT + normalized transpose Tnt ----------------
__global__ __launch_bounds__(256) void k_tnorm(const float* T_, u16* Tnt, float* rT, int bo){
  __shared__ float red[16][16][5];
  __shared__ float rn[64];
  __shared__ u16 tile[64][68];
  int b = blockIdx.y; int l0 = blockIdx.x * 64;
  const float* Tb = T_ + (long)(bo + b) * DIM * L;
  int q = threadIdx.x & 15, g = threadIdx.x >> 4;
  f32x4 ss = {0.f, 0.f, 0.f, 0.f};
  for (int d = g; d < DIM; d += 16){
    float4 v = *(const float4*)(Tb + (long)d * L + l0 + q * 4);
    f32x4 vv = {v.x, v.y, v.z, v.w};
    ss += vv * vv;
  }
  #pragma unroll
  for (int e = 0; e < 4; e++) red[g][q][e] = ss[e];
  __syncthreads();
  if (threadIdx.x < 64){
    int c = threadIdx.x;
    float n = 0.f;
    #pragma unroll
    for (int gg = 0; gg < 16; gg++) n += red[gg][c >> 2][c & 3];
    float r = 1.0f / fmaxf(sqrtf(n), 1e-12f);
    rn[c] = r;
    rT[(long)b * L + l0 + c] = r;
  }
  __syncthreads();
  float r0 = rn[q * 4], r1 = rn[q * 4 + 1], r2 = rn[q * 4 + 2], r3 = rn[q * 4 + 3];
  u16* Tntb = Tnt + (long)b * L * DIM;
  for (int ch = 0; ch < 16; ch++){
    int dbase = ch * 64;
    for (int r = g; r < 64; r += 16){
      float4 v = *(const float4*)(Tb + (long)(dbase + r) * L + l0 + q * 4);
      ushort4 h;
      h.x = f2bf(v.x * r0); h.y = f2bf(v.y * r1);
      h.z = f2bf(v.z * r2); h.w = f2bf(v.w * r3);
      *(ushort4*)&tile[r][q * 4] = h;
    }
    __syncthreads();
    for (int r = g; r < 64; r += 16){
      ushort4 h;
      h.x = tile[q * 4 + 0][r]; h.y = tile[q * 4 + 1][r];
      h.z = tile[q * 4 + 2][r]; h.w = tile[q * 4 + 3][r];
      *(ushort4*)&Tntb[(long)(l0 + r) * DIM + dbase + q * 4] = h;
    }
    __syncthreads();
  }
}

// ================= 256x256 8-phase bt-GEMM =================
// C[m,n] = epi( sum_k A[m,k]*B[n,k] ), M=N=K=1024 per batch.
// 512 threads (8 waves 2Mx4N), BK=64, dbuf LDS 128KiB, XOR-swizzled.
// EPI: 0 relu | 1 exp(acc*scale) | 2 relu * Zinv[n] | 3 plain

#define PH(slot, mq, nq, STAGE, WAITC) do {                                   \
  s16x8 av[4][2], bv[2][2];                                                   \
  _Pragma("unroll")                                                           \
  for (int f = 0; f < 4; f++){                                                \
    av[f][0] = *(const s16x8*)&lds[(slot)*16384 + arow + (mq)*4096 + f*1024 + cko0]; \
    av[f][1] = *(const s16x8*)&lds[(slot)*16384 + arow + (mq)*4096 + f*1024 + cko1]; \
  }                                                                           \
  _Pragma("unroll")                                                           \
  for (int g = 0; g < 2; g++){                                                \
    bv[g][0] = *(const s16x8*)&lds[32768 + (slot)*16384 + brow + (nq)*2048 + g*1024 + cko0]; \
    bv[g][1] = *(const s16x8*)&lds[32768 + (slot)*16384 + brow + (nq)*2048 + g*1024 + cko1]; \
  }                                                                           \
  STAGE;                                                                      \
  WAITC;                                                                      \
  __builtin_amdgcn_s_barrier();                                               \
  asm volatile("s_waitcnt lgkmcnt(0)" ::: "memory");                          \
  __builtin_amdgcn_sched_barrier(0);                                          \
  __builtin_amdgcn_s_setprio(1);                                              \
  _Pragma("unroll")                                                           \
  for (int f = 0; f < 4; f++)                                                 \
    _Pragma("unroll")                                                         \
    for (int g = 0; g < 2; g++){                                              \
      acc[(mq)*4+f][(nq)*2+g] = __builtin_amdgcn_mfma_f32_16x16x32_bf16(      \
          av[f][0], bv[g][0], acc[(mq)*4+f][(nq)*2+g], 0, 0, 0);              \
      acc[(mq)*4+f][(nq)*2+g] = __builtin_amdgcn_mfma_f32_16x16x32_bf16(      \
          av[f][1], bv[g][1], acc[(mq)*4+f][(nq)*2+g], 0, 0, 0);              \
    }                                                                         \
  __builtin_amdgcn_s_setprio(0);                                              \
  __builtin_amdgcn_s_barrier();                                               \
} while(0)

template<int EPI>
__global__ __launch_bounds__(512, 2) void k_gemm2(const u16* A, const u16* B, u16* C,
                                                  long sA_, long sB_, long sC_,
                                                  const float* Zp, float scale){
  constexpr int K = 1024, NN = 1024, NT = K / 64, NIT = NT / 2;
  __shared__ u16 lds[65536];  // [A s0|A s1|B s0|B s1] x 16384 u16 = 128 KiB

  int tid = threadIdx.x;
  int w = tid >> 6, l = tid & 63;
  int wr = w >> 2, wc = w & 3;
  int lr = l & 15, cb = l >> 4;

  // bijective XCD swizzle (nwg % 8 == 0 always: nwg = 16*G)
  int nwg = gridDim.x, cpx = nwg >> 3;
  int swz = (blockIdx.x & 7) * cpx + (blockIdx.x >> 3);
  int batch = swz >> 4;
  int tile = swz & 15;
  int bm = (tile >> 2) * 256, bn = (tile & 3) * 256;

  const u16* Ab = A + (long)batch * sA_ + (long)bm * K;
  const u16* Bb = B + (long)batch * sB_ + (long)bn * K;

  // ds_read constants (u16 units); row&7 == lr&7 for all fragment rows
  int arow = (wr * 128 + lr) * 64;
  int brow = (wc * 64 + lr) * 64;
  int cko0 = ((cb) ^ (lr & 7)) * 8;
  int cko1 = ((4 + cb) ^ (lr & 7)) * 8;

  // stage constants: lane l sources row +=(l>>3), chunk (l&7)^(l>>3)
  int srow8 = l >> 3;
  int schunk = (l & 7) ^ (l >> 3);

  auto stA = [&](int slot, int t, int q){
    #pragma unroll
    for (int j = 0; j < 2; j++){
      int wb = w * 2 + j;
      int gr = ((wb >> 3) * 128) + ((wb & 7) * 8) + q * 64;
      gload_lds16(Ab + (long)(gr + srow8) * K + t * 64 + schunk * 8,
                  (u16*)lds + slot * 16384 + gr * 64);
    }
  };
  auto stB = [&](int slot, int t, int q){
    #pragma unroll
    for (int j = 0; j < 2; j++){
      int wb = w * 2 + j;
      int gr = ((wb >> 2) * 64) + ((wb & 3) * 8) + q * 32;
      gload_lds16(Bb + (long)(gr + srow8) * K + t * 64 + schunk * 8,
                  (u16*)lds + 32768 + slot * 16384 + gr * 64);
    }
  };

  f32x4 acc[8][4] = {};

  // prologue: tile0 -> slot0 (all 4 units), tile1 -> slot1 (A0,B0)
  stA(0, 0, 0); stB(0, 0, 0); stA(0, 0, 1); stB(0, 0, 1);
  stA(1, 1, 0); stB(1, 1, 0);
  asm volatile("s_waitcnt vmcnt(4)" ::: "memory");
  __builtin_amdgcn_s_barrier();

  #pragma unroll 1
  for (int i = 0; i < NIT - 1; ++i){
    int t1 = 2 * i + 1, t2 = 2 * i + 2, t3 = 2 * i + 3;
    PH(0, 0, 0, stA(1, t1, 1), (void)0);
    PH(0, 0, 1, stB(1, t1, 1), (void)0);
    PH(0, 1, 0, stA(0, t2, 0), (void)0);
    PH(0, 1, 1, stB(0, t2, 0), asm volatile("s_waitcnt vmcnt(4)" ::: "memory"));
    PH(1, 0, 0, stA(0, t2, 1), (void)0);
    PH(1, 0, 1, stB(0, t2, 1), (void)0);
    PH(1, 1, 0, stA(1, t3, 0), (void)0);
    PH(1, 1, 1, stB(1, t3, 0), asm volatile("s_waitcnt vmcnt(4)" ::: "memory"));
  }
  // peeled last iteration: no t2/t3 prefetch, drain at phase 4
  {
    int t1 = NT - 1;
    PH(0, 0, 0, stA(1, t1, 1), (void)0);
    PH(0, 0, 1, stB(1, t1, 1), (void)0);
    PH(0, 1, 0, (void)0, (void)0);
    PH(0, 1, 1, (void)0, asm volatile("s_waitcnt vmcnt(0)" ::: "memory"));
    PH(1, 0, 0, (void)0, (void)0);
    PH(1, 0, 1, (void)0, (void)0);
    PH(1, 1, 0, (void)0, (void)0);
    PH(1, 1, 1, (void)0, (void)0);
  }

  // epilogue
  float iz[4];
  if (EPI == 2){
    #pragma unroll
    for (int j = 0; j < 4; j++)
      iz[j] = Zp[(long)batch * NN + bn + wc * 64 + j * 16 + lr];
  }
  u16* Cb = C + (long)batch * sC_;
  int cb4 = cb * 4;
  #pragma unroll
  for (int ai = 0; ai < 8; ai++)
    #pragma unroll
    for (int j = 0; j < 4; j++)
      #pragma unroll
      for (int r = 0; r < 4; r++){
        float v = acc[ai][j][r];
        if (EPI == 0) v = fmaxf(v, 0.f);
        else if (EPI == 1) v = __expf(v * scale);
        else if (EPI == 2) v = fmaxf(v, 0.f) * iz[j];
        int row = bm + wr * 128 + ai * 16 + cb4 + r;
        int col = bn + wc * 64 + j * 16 + lr;
        Cb[(long)row * NN + col] = f2bf(v);
      }
}

// ---------------- column sums of E[q,k] over q -> invZ[k] (vectorized) ----------------
__global__ __launch_bounds__(256) void k_colsum(const u16* E, float* invZ){
  __shared__ float red[32][8][9];
  int b = blockIdx.y; int k0 = blockIdx.x * 64;
  const u16* Eb = E + (long)b * L * L + k0;
  int co = threadIdx.x & 7, g = threadIdx.x >> 3;
  float z[8] = {0.f, 0.f, 0.f, 0.f, 0.f, 0.f, 0.f, 0.f};
  for (int qq = g; qq < L; qq += 32){
    s16x8 h = *(const s16x8*)(Eb + (long)qq * L + co * 8);
    #pragma unroll
    for (int e = 0; e < 8; e++) z[e] += bf2f((u16)h[e]);
  }
  #pragma unroll
  for (int e = 0; e < 8; e++) red[g][co][e] = z[e];
  __syncthreads();
  if (threadIdx.x < 64){
    int c = threadIdx.x;
    float s = 0.f;
    #pragma unroll
    for (int gg = 0; gg < 32; gg++) s += red[gg][c >> 3][c & 7];
    invZ[(long)b * L + k0 + c] = 1.0f / s;
  }
}

// ---------------- final: out = l2n(l2n(V+w1t) + l2n(T*rT+w2t)) per column ----------------
__global__ __launch_bounds__(1024) void k_final(const float* V, const float* T_,
                                                const float* rT, const u16* w1t,
                                                const u16* w2t, float* out, int bo){
  __shared__ float red[64][16][13];
  __shared__ float fac[3][64];
  int b = blockIdx.y;
  int c0 = blockIdx.x * 64;
  long gbase = (long)(bo + b) * DIM * L + c0;
  long lbase = (long)b * DIM * L + c0;
  int cq = threadIdx.x & 15, g = threadIdx.x >> 4;
  int coff = cq * 4;
  float4 rt4 = *(const float4*)(rT + (long)b * L + c0 + coff);
  f32x4 rtv = {rt4.x, rt4.y, rt4.z, rt4.w};
  f32x4 s1 = {0.f,0.f,0.f,0.f}, s2 = {0.f,0.f,0.f,0.f}, s12 = {0.f,0.f,0.f,0.f};
  for (int d = g; d < DIM; d += 64){
    long o = (long)d * L + coff;
    float4 v = *(const float4*)(V + gbase + o);
    float4 t = *(const float4*)(T_ + gbase + o);
    ushort4 w1 = *(const ushort4*)(w1t + lbase + o);
    ushort4 w2 = *(const ushort4*)(w2t + lbase + o);
    f32x4 a = {v.x + bf2f(w1.x), v.y + bf2f(w1.y), v.z + bf2f(w1.z), v.w + bf2f(w1.w)};
    f32x4 tt = {t.x, t.y, t.z, t.w};
    f32x4 bb = tt * rtv;
    bb[0] += bf2f(w2.x); bb[1] += bf2f(w2.y); bb[2] += bf2f(w2.z); bb[3] += bf2f(w2.w);
    s1 += a * a; s2 += bb * bb; s12 += a * bb;
  }
  #pragma unroll
  for (int e = 0; e < 4; e++){
    red[g][cq][e] = s1[e];
    red[g][cq][4 + e] = s2[e];
    red[g][cq][8 + e] = s12[e];
  }
  __syncthreads();
  if (threadIdx.x < 192){
    int q = threadIdx.x / 12, s = threadIdx.x % 12;
    float acc = 0.f;
    #pragma unroll 8
    for (int gg = 0; gg < 64; gg++) acc += red[gg][q][s];
    red[0][q][s] = acc;
  }
  __syncthreads();
  if (threadIdx.x < 64){
    int c = threadIdx.x;
    float n1 = red[0][c >> 2][c & 3];
    float n2 = red[0][c >> 2][4 + (c & 3)];
    float cc = red[0][c >> 2][8 + (c & 3)];
    float rn1 = 1.f / fmaxf(sqrtf(n1), 1e-12f);
    float rn2 = 1.f / fmaxf(sqrtf(n2), 1e-12f);
    float n3 = n1 * rn1 * rn1 + 2.f * cc * rn1 * rn2 + n2 * rn2 * rn2;
    float rn3 = 1.f / fmaxf(sqrtf(n3), 1e-12f);
    fac[0][c] = rn1; fac[1][c] = rn2; fac[2][c] = rn3;
  }
  __syncthreads();
  f32x4 f1, f2, f3;
  #pragma unroll
  for (int e = 0; e < 4; e++){
    f1[e] = fac[0][coff + e]; f2[e] = fac[1][coff + e]; f3[e] = fac[2][coff + e];
  }
  for (int d = g; d < DIM; d += 64){
    long o = (long)d * L + coff;
    float4 v = *(const float4*)(V + gbase + o);
    float4 t = *(const float4*)(T_ + gbase + o);
    ushort4 w1 = *(const ushort4*)(w1t + lbase + o);
    ushort4 w2 = *(const ushort4*)(w2t + lbase + o);
    f32x4 a = {v.x + bf2f(w1.x), v.y + bf2f(w1.y), v.z + bf2f(w1.z), v.w + bf2f(w1.w)};
    f32x4 tt = {t.x, t.y, t.z, t.w};
    f32x4 bb = tt * rtv;
    bb[0] += bf2f(w2.x); bb[1] += bf2f(w2.y); bb[2] += bf2f(w2.z); bb[3] += bf2f(w2.w);
    f32x4 r = (a * f1 + bb * f2) * f3;
    float4 st = {r[0], r[1], r[2], r[3]};
    *(float4*)(out + gbase + o) = st;
  }
}

extern "C" void kernel_launch(void* const* d_in, const int* in_sizes, int n_in,
                              void* d_out, int out_size, void* d_ws, size_t ws_size,
                              hipStream_t stream) {
  const float* V = (const float*)d_in[0];
  const float* T = (const float*)d_in[1];
  char* ws = (char*)d_ws;
  const long MB = 1 << 20;
  float* out = (float*)d_out;

  // pick batch-group size so workspace fits: fixed 13MB + 14MB per batch
  int G = NB;
  while (G > 1 && (size_t)((13 + 14 * (long)G) * MB) > ws_size) G >>= 1;

  u16*   Wb   = (u16*)(ws);                          // 12MB (6 x 1M bf16)
  float* rT   = (float*)(ws + 12 * MB);              // G*L f32 (<=64KB)
  float* invZ = (float*)(ws + 12 * MB + 512 * 1024); // G*L f32 (<=64KB)
  char*  bufs = ws + 13 * MB;
  long   BUF  = (long)G * 2 * MB;                    // per-buffer bytes
  u16* Vt  = (u16*)(bufs);
  u16* Tnt = (u16*)(bufs + 1 * BUF);
  u16* qb  = (u16*)(bufs + 2 * BUF);   // also holds v1t'/v2t' (overlay)
  u16* kb  = (u16*)(bufs + 3 * BUF);
  u16* Eb  = (u16*)(bufs + 4 * BUF);
  u16* w1b = (u16*)(bufs + 5 * BUF);
  u16* w2b = (u16*)(bufs + 6 * BUF);

  WPtrs wp;
  for (int i = 0; i < 6; i++) wp.p[i] = (const float*)d_in[2 + i];
  const u16* WQ1 = Wb + 0L * MB; const u16* WK1 = Wb + 1L * MB;
  const u16* WV1 = Wb + 2L * MB; const u16* Wq2 = Wb + 3L * MB;
  const u16* Wk2 = Wb + 4L * MB; const u16* Wv2 = Wb + 5L * MB;

  long LD = (long)L * DIM, LL = (long)L * L;
  const float invsq = 0.03125f;  // 1/sqrt(1024)

  k_wconv<<<6144, 256, 0, stream>>>(wp, Wb);

  for (int bo = 0; bo < NB; bo += G){
    int ng = 16 * G;  // 4x4 tiles per batch
    k_transpose<<<dim3(256, G), 256, 0, stream>>>(V, Vt, bo);
    k_tnorm<<<dim3(16, G), 256, 0, stream>>>(T, Tnt, rT, bo);

    // side 1
    k_gemm2<0><<<ng, 512, 0, stream>>>(Vt,  WQ1, qb, LD, 0, LD, nullptr, 0.f);   // q1[l,e]
    k_gemm2<0><<<ng, 512, 0, stream>>>(Tnt, WK1, kb, LD, 0, LD, nullptr, 0.f);   // k1[l,e]
    k_gemm2<1><<<ng, 512, 0, stream>>>(qb, kb, Eb, LD, LD, LL, nullptr, invsq);  // E=exp(S)
    k_colsum<<<dim3(16, G), 256, 0, stream>>>(Eb, invZ);
    k_gemm2<2><<<ng, 512, 0, stream>>>(WV1, Tnt, qb, 0, LD, LD, invZ, 0.f);      // v1t'[e,k]
    k_gemm2<3><<<ng, 512, 0, stream>>>(qb, Eb, w1b, LD, LL, LD, nullptr, 0.f);   // w1t[e,q]

    // side 2
    k_gemm2<0><<<ng, 512, 0, stream>>>(Tnt, Wq2, qb, LD, 0, LD, nullptr, 0.f);   // q2[l,e]
    k_gemm2<0><<<ng, 512, 0, stream>>>(Vt,  Wk2, kb, LD, 0, LD, nullptr, 0.f);   // k2[l,e]
    k_gemm2<1><<<ng, 512, 0, stream>>>(qb, kb, Eb, LD, LD, LL, nullptr, invsq);
    k_colsum<<<dim3(16, G), 256, 0, stream>>>(Eb, invZ);
    k_gemm2<2><<<ng, 512, 0, stream>>>(Wv2, Vt, qb, 0, LD, LD, invZ, 0.f);       // v2t'[e,k]
    k_gemm2<3><<<ng, 512, 0, stream>>>(qb, Eb, w2b, LD, LL, LD, nullptr, 0.f);   // w2t[e,q]

    k_final<<<dim3(16, G), 1024, 0, stream>>>(V, T, rT, w1b, w2b, out, bo);
  }
}